// Round 9
// baseline (2094.200 us; speedup 1.0000x reference)
//
#include <hip/hip_runtime.h>

#define N_NODES 50000
#define E1N 1600000
#define M_PAIRS 200000
#define E2N 3200000
#define P_OUT 20000
#define EPSF 1e-5f

#define RED_BLOCKS 512
#define TB 64                  // dest-tile (bucket) size in nodes
#define B1T 782                // ceil(N_NODES/64)
#define B2T 3125               // ceil(M_PAIRS/64)
#define NBKT (B1T + B2T)       // 3907
#define PCHUNK 8192            // edges per partition block

// ---------------- stats offsets within stats buffer (floats) ----------------
#define S0_SUM   0
#define S0_SQ    32
#define S_A0     64
#define S_B0ROW  96
#define S_A1     192
#define S_B1     224
#define S_CNT    256   // int
#define S_ZC0    288
#define S_ZC1    320
#define S_A3     416
#define S_B3     448
#define S_TOTAL  512

__device__ __forceinline__ void f4add(float4& a, const float4 b) {
    a.x += b.x; a.y += b.y; a.z += b.z; a.w += b.w;
}

// block-level reduce of per-thread float4 partials (feature group = (tid&7)*4)
__device__ __forceinline__ void stats_block_reduce(float4 s, float4 q,
                                                   float* __restrict__ sum,
                                                   float* __restrict__ sumsq) {
    __shared__ float4 ss[256], sq[256];
    int tid = threadIdx.x;
    ss[tid] = s; sq[tid] = q;
    __syncthreads();
    #pragma unroll
    for (int st = 128; st >= 8; st >>= 1) {
        if (tid < st) { f4add(ss[tid], ss[tid + st]); f4add(sq[tid], sq[tid + st]); }
        __syncthreads();
    }
    if (tid < 8) {
        int base = tid * 4;
        float4 fs = ss[tid], fq = sq[tid];
        atomicAdd(&sum[base + 0], fs.x);
        atomicAdd(&sum[base + 1], fs.y);
        atomicAdd(&sum[base + 2], fs.z);
        atomicAdd(&sum[base + 3], fs.w);
        atomicAdd(&sumsq[base + 0], fq.x);
        atomicAdd(&sumsq[base + 1], fq.y);
        atomicAdd(&sumsq[base + 2], fq.z);
        atomicAdd(&sumsq[base + 3], fq.w);
    }
}

// gather embedding rows (float4 granularity), store e, accumulate gn0 stats
__global__ void k_embed_stats(const float* __restrict__ emb, const int* __restrict__ x,
                              float* __restrict__ e, float* __restrict__ sum,
                              float* __restrict__ sumsq, int n) {
    long n4 = (long)n * 8;
    float4 s = {0,0,0,0}, q = {0,0,0,0};
    float4* e4 = (float4*)e;
    long stride = (long)gridDim.x * 256;
    for (long i = (long)blockIdx.x * 256 + threadIdx.x; i < n4; i += stride) {
        int node = (int)(i >> 3), fg = ((int)i & 7) * 4;
        int xr = x[node];
        float4 v = *(const float4*)&emb[(long)xr * 32 + fg];
        e4[i] = v;
        s.x += v.x; s.y += v.y; s.z += v.z; s.w += v.w;
        q.x += v.x * v.x; q.y += v.y * v.y; q.z += v.z * v.z; q.w += v.w * v.w;
    }
    stats_block_reduce(s, q, sum, sumsq);
}

// gn0 affine + fold shift through c1_W (atomic-accumulated stats)
__global__ void k_affine_fold(const float* __restrict__ sum, const float* __restrict__ sumsq,
                              const float* __restrict__ w, const float* __restrict__ b,
                              const float* __restrict__ ms, float invN,
                              const float* __restrict__ W,
                              float* __restrict__ A, float* __restrict__ brow) {
    __shared__ float Bl[32];
    int f = threadIdx.x;  // 32 threads
    float mean = sum[f] * invN;
    float c = ms[f] * mean;
    float var = sumsq[f] * invN - 2.f * c * mean + c * c;
    float rs = rsqrtf(var + EPSF);
    A[f] = w[f] * rs;
    Bl[f] = b[f] - w[f] * rs * c;
    __syncthreads();
    float s = 0.f;
    #pragma unroll
    for (int f2 = 0; f2 < 32; f2++) s += Bl[f2] * W[f2 * 32 + f];
    brow[f] = s;
}

// GraphNorm affine from PER-BLOCK PARTIAL stats: pstat[i*64 + f] = sum, [i*64+32+f] = sq
__global__ void k_affine_part(const float* __restrict__ pstat, int nblk,
                              const float* __restrict__ w, const float* __restrict__ b,
                              const float* __restrict__ ms, float invN,
                              float* __restrict__ A, float* __restrict__ B) {
    int f = threadIdx.x;  // 32 threads
    float s = 0.f, q = 0.f;
    for (int i = 0; i < nblk; i++) {
        s += pstat[i * 64 + f];
        q += pstat[i * 64 + 32 + f];
    }
    float mean = s * invN;
    float c = ms[f] * mean;
    float var = q * invN - 2.f * c * mean + c * c;
    float rs = rsqrtf(var + EPSF);
    A[f] = w[f] * rs;
    B[f] = b[f] - w[f] * rs * c;
}

// u[i][o] = (sum_f (A[f]*e[i][f]) * W[f][o] + brow[o]) * dscale[i]
__global__ void k_mm32s(const float* __restrict__ e, const float* __restrict__ W,
                        const float* __restrict__ A, const float* __restrict__ brow,
                        const float* __restrict__ dscale, float* __restrict__ t, int n) {
    __shared__ float Wp[32][32];
    __shared__ float rows[8][32];
    int lt = threadIdx.x;
    for (int k = lt; k < 1024; k += 256) {
        int f = k >> 5;
        Wp[f][k & 31] = A[f] * W[k];
    }
    int nl = lt >> 5, o = lt & 31;
    int node = blockIdx.x * 8 + nl;
    if (node < n) rows[nl][o] = e[(long)node * 32 + o];
    __syncthreads();
    if (node < n) {
        float acc = brow[o];
        #pragma unroll
        for (int f = 0; f < 32; f++) acc += rows[nl][f] * Wp[f][o];
        t[(long)node * 32 + o] = acc * dscale[node];
    }
}

// hw[i][o] = sum_f relu(A[f]*g[i][f]+B[f]) * W[f][o]   (fused gn1 affine+ReLU)
__global__ void k_mm32_relu_in(const float* __restrict__ g, const float* __restrict__ W,
                               const float* __restrict__ A, const float* __restrict__ B,
                               float* __restrict__ hw, int n) {
    __shared__ float Wp[32][32];
    __shared__ float rows[8][32];
    int lt = threadIdx.x;
    for (int k = lt; k < 1024; k += 256) {
        Wp[k >> 5][k & 31] = W[k];
    }
    int nl = lt >> 5, o = lt & 31;
    int node = blockIdx.x * 8 + nl;
    if (node < n) rows[nl][o] = fmaxf(A[o] * g[(long)node * 32 + o] + B[o], 0.f);
    __syncthreads();
    if (node < n) {
        float acc = 0.f;
        #pragma unroll
        for (int f = 0; f < 32; f++) acc += rows[nl][f] * Wp[f][o];
        hw[(long)node * 32 + o] = acc;
    }
}

// ---------------- binned aggregation machinery ----------------

// per-bucket edge counts (LDS histogram, one flush per block; 128 blocks)
__global__ void k_bcount(const int* __restrict__ e1col, const int* __restrict__ e2col,
                         int* __restrict__ bcnt) {
    __shared__ int hist[NBKT];
    for (int i = threadIdx.x; i < NBKT; i += 256) hist[i] = 0;
    __syncthreads();
    long total = (long)E1N + E2N;
    for (long i = (long)blockIdx.x * 256 + threadIdx.x; i < total; i += (long)gridDim.x * 256) {
        int b;
        if (i < E1N) b = e1col[i] >> 6;
        else         b = B1T + (e2col[i - E1N] >> 6);
        atomicAdd(&hist[b], 1);
    }
    __syncthreads();
    for (int i = threadIdx.x; i < NBKT; i += 256)
        if (hist[i]) atomicAdd(&bcnt[i], hist[i]);
}

// exclusive scan of bucket counts (single block, 1024 thr x 4); bbase[NBKT]=total
__global__ void k_bscan(const int* __restrict__ bcnt, int* __restrict__ bbase) {
    __shared__ int sd[1024];
    int t = threadIdx.x;
    int v[4]; int s = 0;
    #pragma unroll
    for (int u = 0; u < 4; u++) {
        int idx = t * 4 + u;
        v[u] = (idx < NBKT) ? bcnt[idx] : 0;
        s += v[u];
    }
    sd[t] = s;
    __syncthreads();
    for (int off = 1; off < 1024; off <<= 1) {
        int a = (t >= off) ? sd[t - off] : 0;
        __syncthreads();
        sd[t] += a;
        __syncthreads();
    }
    int run = sd[t] - s;
    #pragma unroll
    for (int u = 0; u < 4; u++) {
        int idx = t * 4 + u;
        if (idx <= NBKT) bbase[idx] = run;
        run += v[u];
    }
}

// partition edges into bucket-contiguous packed records (row<<6 | c_lo)
__global__ void k_partition(const int* __restrict__ row, const int* __restrict__ col,
                            int ne, int bucket0, int nbk,
                            int* __restrict__ cursor, const int* __restrict__ bbase,
                            int* __restrict__ recs) {
    __shared__ int hist[B2T];
    __shared__ int rbase[B2T];
    for (int i = threadIdx.x; i < nbk; i += 256) hist[i] = 0;
    __syncthreads();
    int c0 = blockIdx.x * PCHUNK;
    int cend = min(c0 + PCHUNK, ne);
    for (int i = c0 + threadIdx.x; i < cend; i += 256)
        atomicAdd(&hist[col[i] >> 6], 1);
    __syncthreads();
    for (int b = threadIdx.x; b < nbk; b += 256) {
        int h = hist[b];
        rbase[b] = h ? bbase[bucket0 + b] + atomicAdd(&cursor[bucket0 + b], h) : 0;
        hist[b] = 0;
    }
    __syncthreads();
    for (int i = c0 + threadIdx.x; i < cend; i += 256) {
        int c = col[i];
        int b = c >> 6;
        int rank = atomicAdd(&hist[b], 1);
        recs[rbase[b] + rank] = (row[i] << 6) | (c & 63);
    }
}

// per-node degrees -> dinv, from binned records via LDS counters
__global__ void k_deg_tiled(const int* __restrict__ recs, const int* __restrict__ bbase,
                            int bucket0, float* __restrict__ dinv, int n) {
    __shared__ int cnt[TB];
    int tid = threadIdx.x;
    if (tid < TB) cnt[tid] = 0;
    __syncthreads();
    int gb = bucket0 + blockIdx.x;
    int beg = bbase[gb], end = bbase[gb + 1];
    for (int i = beg + tid; i < end; i += 256)
        atomicAdd(&cnt[recs[i] & 63], 1);
    __syncthreads();
    int c = blockIdx.x * TB + tid;
    if (tid < TB && c < n) dinv[c] = rsqrtf((float)cnt[tid] + 1.f);
}

// tile aggregation v3: 256 thr (8 half-waves), BRANCH-FREE register unroll-8 for
// true 8-deep MLP per half-wave. LDS fp32 accumulator per 64-node dest tile.
// Epilogue fuses self-loop + bias + dinv scaling; writes per-block partial stats.
__global__ __launch_bounds__(256) void k_tile_agg(
        const int* __restrict__ recs, const int* __restrict__ bbase, int bucket0,
        const float* __restrict__ u, const float* __restrict__ dinv,
        const float* __restrict__ bias, float* __restrict__ aggout,
        float* __restrict__ pstat, int n) {
    __shared__ float acc[TB][32];   // 8 KB
    int tid = threadIdx.x;
    float4* a4 = (float4*)&acc[0][0];
    for (int i = tid; i < TB * 8; i += 256) a4[i] = make_float4(0.f, 0.f, 0.f, 0.f);
    __syncthreads();
    int gb = bucket0 + blockIdx.x;
    int beg = bbase[gb], end = bbase[gb + 1];
    int hwid = tid >> 5;        // half-wave id 0..7
    int f = tid & 31;
    int cnt = end - beg;
    int nfull = cnt & ~63;      // multiple of 64
    const float* uf = u + f;
    // main loop: branch-free, 8 independent record streams per half-wave
    for (int base = beg + hwid * 8; base < beg + nfull; base += 64) {
        int r0 = recs[base + 0];
        int r1 = recs[base + 1];
        int r2 = recs[base + 2];
        int r3 = recs[base + 3];
        int r4 = recs[base + 4];
        int r5 = recs[base + 5];
        int r6 = recs[base + 6];
        int r7 = recs[base + 7];
        float v0 = uf[(long)(r0 >> 6) * 32];
        float v1 = uf[(long)(r1 >> 6) * 32];
        float v2 = uf[(long)(r2 >> 6) * 32];
        float v3 = uf[(long)(r3 >> 6) * 32];
        float v4 = uf[(long)(r4 >> 6) * 32];
        float v5 = uf[(long)(r5 >> 6) * 32];
        float v6 = uf[(long)(r6 >> 6) * 32];
        float v7 = uf[(long)(r7 >> 6) * 32];
        atomicAdd(&acc[r0 & 63][f], v0);
        atomicAdd(&acc[r1 & 63][f], v1);
        atomicAdd(&acc[r2 & 63][f], v2);
        atomicAdd(&acc[r3 & 63][f], v3);
        atomicAdd(&acc[r4 & 63][f], v4);
        atomicAdd(&acc[r5 & 63][f], v5);
        atomicAdd(&acc[r6 & 63][f], v6);
        atomicAdd(&acc[r7 & 63][f], v7);
    }
    // tail (< 64 records)
    for (int i = beg + nfull + hwid; i < end; i += 8) {
        int rec = recs[i];
        atomicAdd(&acc[rec & 63][f], uf[(long)(rec >> 6) * 32]);
    }
    __syncthreads();
    float sacc = 0.f, qacc = 0.f;
    int tile0 = blockIdx.x * TB;
    float bf = bias[f];
    for (int rw = hwid; rw < TB; rw += 8) {
        int c = tile0 + rw;
        if (c < n) {
            float dc = dinv[c];
            float a = dc * (acc[rw][f] + u[(long)c * 32 + f]) + bf;
            aggout[(long)c * 32 + f] = a;
            sacc += a;
            qacc += a * a;
        }
    }
    __syncthreads();
    float* red = &acc[0][0];
    red[tid] = sacc;
    __syncthreads();
    if (tid < 32) {
        float s = 0.f;
        #pragma unroll
        for (int k = 0; k < 8; k++) s += red[tid + k * 32];
        pstat[blockIdx.x * 64 + tid] = s;
    }
    __syncthreads();
    red[tid] = qacc;
    __syncthreads();
    if (tid < 32) {
        float q = 0.f;
        #pragma unroll
        for (int k = 0; k < 8; k++) q += red[tid + k * 32];
        pstat[blockIdx.x * 64 + 32 + tid] = q;
    }
}

__global__ void k_mask(const int* __restrict__ pos2, int* __restrict__ mask, int p) {
    int i = blockIdx.x * 256 + threadIdx.x;
    if (i < p) mask[pos2[i]] = 1;
}

__global__ void k_maskcnt(const int* __restrict__ mask, int* __restrict__ cnt, int m) {
    __shared__ int sd[256];
    int idx = blockIdx.x * 256 + threadIdx.x;
    sd[threadIdx.x] = (idx < m) ? mask[idx] : 0;
    __syncthreads();
    for (int s = 128; s > 0; s >>= 1) {
        if (threadIdx.x < s) sd[threadIdx.x] += sd[threadIdx.x + s];
        __syncthreads();
    }
    if (threadIdx.x == 0) atomicAdd(cnt, sd[0]);
}

// z has only two distinct rows (mask 0/1); zc{0,1}[o] = z{0,1} @ c2_W[32:48]
__global__ void k_zcalc(const float* __restrict__ emb2, const float* __restrict__ w,
                        const float* __restrict__ b, const float* __restrict__ ms,
                        const int* __restrict__ cnt, const float* __restrict__ c2W,
                        float* __restrict__ zc0, float* __restrict__ zc1) {
    __shared__ float z0[16], z1[16];
    int t = threadIdx.x;  // 32 threads
    const float Mf = (float)M_PAIRS;
    if (t < 16) {
        float e0 = emb2[t], e1 = emb2[16 + t];
        float c1f = (float)(*cnt);
        float mean = (c1f * e1 + (Mf - c1f) * e0) / Mf;
        float c = ms[t] * mean;
        float d0 = e0 - c, d1 = e1 - c;
        float var = (c1f * d1 * d1 + (Mf - c1f) * d0 * d0) / Mf;
        float rs = rsqrtf(var + EPSF);
        z0[t] = w[t] * d0 * rs + b[t];
        z1[t] = w[t] * d1 * rs + b[t];
    }
    __syncthreads();
    float s0 = 0.f, s1 = 0.f;
    #pragma unroll
    for (int f = 0; f < 16; f++) {
        float wv = c2W[(32 + f) * 32 + t];
        s0 += z0[f] * wv;
        s1 += z1[f] * wv;
    }
    zc0[t] = s0;
    zc1[t] = s1;
}

// t2[j][fg..] = (hw[a][fg..] + hw[b][fg..] + zc_{mask[j]}[fg..]) * d2[j]
__global__ void k_t2(const float* __restrict__ hw, const int* __restrict__ pos1,
                     const int* __restrict__ mask, const float* __restrict__ zc0,
                     const float* __restrict__ zc1, const float* __restrict__ d2,
                     float* __restrict__ t2, int m) {
    long idx = (long)blockIdx.x * 256 + threadIdx.x;
    if (idx >= (long)m * 8) return;
    int j = (int)(idx >> 3), fg = ((int)idx & 7) * 4;
    int a = pos1[2 * j], b = pos1[2 * j + 1];
    const float* zc = mask[j] ? zc1 : zc0;
    float dj = d2[j];
    float4 va = *(const float4*)&hw[(long)a * 32 + fg];
    float4 vb = *(const float4*)&hw[(long)b * 32 + fg];
    float4 vz = *(const float4*)&zc[fg];
    float4 r;
    r.x = (va.x + vb.x + vz.x) * dj;
    r.y = (va.y + vb.y + vz.y) * dj;
    r.z = (va.z + vb.z + vz.z) * dj;
    r.w = (va.w + vb.w + vz.w) * dj;
    *(float4*)&t2[idx * 4] = r;
}

// out[k] = relu(A*g2[pos2[k]]+B) . predW + predb
__global__ void k_pred(const float* __restrict__ g2, const int* __restrict__ pos2,
                       const float* __restrict__ A, const float* __restrict__ B,
                       const float* __restrict__ predW, const float* __restrict__ predb,
                       float* __restrict__ out, int p) {
    int k = blockIdx.x * 256 + threadIdx.x;
    if (k >= p) return;
    int j = pos2[k];
    float s = predb[0];
    #pragma unroll
    for (int o = 0; o < 32; o++)
        s += fmaxf(A[o] * g2[(long)j * 32 + o] + B[o], 0.f) * predW[o];
    out[k] = s;
}

extern "C" void kernel_launch(void* const* d_in, const int* in_sizes, int n_in,
                              void* d_out, int out_size, void* d_ws, size_t ws_size,
                              hipStream_t stream) {
    const int*   x      = (const int*)d_in[0];
    const int*   e1row  = (const int*)d_in[1];
    const int*   e1col  = e1row + E1N;
    const int*   e2row  = (const int*)d_in[2];
    const int*   e2col  = e2row + E2N;
    const int*   pos1   = (const int*)d_in[3];
    const int*   pos2   = (const int*)d_in[4];
    const float* emb1   = (const float*)d_in[5];
    const float* gn0_w  = (const float*)d_in[6];
    const float* gn0_b  = (const float*)d_in[7];
    const float* gn0_ms = (const float*)d_in[8];
    const float* c1_W   = (const float*)d_in[9];
    const float* c1_b   = (const float*)d_in[10];
    const float* gn1_w  = (const float*)d_in[11];
    const float* gn1_b  = (const float*)d_in[12];
    const float* gn1_ms = (const float*)d_in[13];
    const float* emb2   = (const float*)d_in[14];
    const float* gn2_w  = (const float*)d_in[15];
    const float* gn2_b  = (const float*)d_in[16];
    const float* gn2_ms = (const float*)d_in[17];
    const float* c2_W   = (const float*)d_in[18];
    const float* c2_b   = (const float*)d_in[19];
    const float* gn3_w  = (const float*)d_in[20];
    const float* gn3_b  = (const float*)d_in[21];
    const float* gn3_ms = (const float*)d_in[22];
    const float* predW  = (const float*)d_in[23];
    const float* predb  = (const float*)d_in[24];
    float* out = (float*)d_out;

    // ---------------- workspace arena (floats) ----------------
    const size_t N32 = (size_t)N_NODES * 32;
    const size_t M32 = (size_t)M_PAIRS * 32;
    float* fw = (float*)d_ws;
    size_t off = 0;
    auto alloc = [&](size_t n) { float* p = fw + off; off += n; return p; };
    float* e      = alloc(N32);               // alias hw later
    float* t      = alloc(N32);               // u1 = gn0(e)@W * dinv
    float* agg    = alloc(N32);
    float* t2     = alloc(M32);               // u2
    float* agg2   = alloc(M32);
    int*   recs   = (int*)alloc((size_t)E1N + E2N);
    float* d1     = alloc(N_NODES);
    float* d2     = alloc(M_PAIRS);
    int*   bbase  = (int*)alloc(NBKT + 2);
    float* pstat1 = alloc((size_t)B1T * 64);
    float* pstat2 = alloc((size_t)B2T * 64);
    // ---- zero region (single memset): bcnt, cursor, mask, stats ----
    int*   bcnt   = (int*)alloc(NBKT + 2);
    int*   cursor = (int*)alloc(NBKT + 2);
    int*   mask   = (int*)alloc(M_PAIRS);
    float* st     = alloc(S_TOTAL);
    float* hw     = e;  // alias: e dead after k_mm32s

    const size_t zero_bytes = (2 * (size_t)(NBKT + 2) + (size_t)M_PAIRS + S_TOTAL) * 4;
    hipMemsetAsync(bcnt, 0, zero_bytes, stream);

    auto cdiv = [](long a, long b) { return (int)((a + b - 1) / b); };
    const float invN = 1.f / (float)N_NODES;
    const float invM = 1.f / (float)M_PAIRS;

    // ---- bin both edge lists by dest tile ----
    k_bcount<<<128, 256, 0, stream>>>(e1col, e2col, bcnt);
    k_bscan<<<1, 1024, 0, stream>>>(bcnt, bbase);
    k_partition<<<cdiv(E1N, PCHUNK), 256, 0, stream>>>(e1row, e1col, E1N, 0,   B1T, cursor, bbase, recs);
    k_partition<<<cdiv(E2N, PCHUNK), 256, 0, stream>>>(e2row, e2col, E2N, B1T, B2T, cursor, bbase, recs);
    k_deg_tiled<<<B1T, 256, 0, stream>>>(recs, bbase, 0,   d1, N_NODES);
    k_deg_tiled<<<B2T, 256, 0, stream>>>(recs, bbase, B1T, d2, M_PAIRS);

    // ---- stage 0: embedding + gn0 stats ----
    k_embed_stats<<<RED_BLOCKS, 256, 0, stream>>>(emb1, x, e, st + S0_SUM, st + S0_SQ, N_NODES);
    k_affine_fold<<<1, 32, 0, stream>>>(st + S0_SUM, st + S0_SQ, gn0_w, gn0_b, gn0_ms, invN,
                                        c1_W, st + S_A0, st + S_B0ROW);

    // ---- conv1: u1 = (gn0(e) @ c1_W) * d1 ; tile aggregation (+gn1 partial stats) ----
    k_mm32s<<<cdiv(N_NODES, 8), 256, 0, stream>>>(e, c1_W, st + S_A0, st + S_B0ROW, d1, t, N_NODES);
    k_tile_agg<<<B1T, 256, 0, stream>>>(recs, bbase, 0, t, d1, c1_b, agg, pstat1, N_NODES);
    k_affine_part<<<1, 32, 0, stream>>>(pstat1, B1T, gn1_w, gn1_b, gn1_ms, invN,
                                        st + S_A1, st + S_B1);
    k_mm32_relu_in<<<cdiv(N_NODES, 8), 256, 0, stream>>>(agg, c2_W, st + S_A1, st + S_B1,
                                                         hw, N_NODES);

    // ---- mask / z path ----
    k_mask<<<cdiv(P_OUT, 256), 256, 0, stream>>>(pos2, mask, P_OUT);
    k_maskcnt<<<cdiv(M_PAIRS, 256), 256, 0, stream>>>(mask, (int*)(st + S_CNT), M_PAIRS);
    k_zcalc<<<1, 32, 0, stream>>>(emb2, gn2_w, gn2_b, gn2_ms, (const int*)(st + S_CNT),
                                  c2_W, st + S_ZC0, st + S_ZC1);

    // ---- conv2: u2 = (hw[a]+hw[b]+zc) * d2 ; tile aggregation (+gn3 partial stats) ----
    k_t2<<<cdiv((long)M_PAIRS * 8, 256), 256, 0, stream>>>(hw, pos1, mask, st + S_ZC0,
                                                           st + S_ZC1, d2, t2, M_PAIRS);
    k_tile_agg<<<B2T, 256, 0, stream>>>(recs, bbase, B1T, t2, d2, c2_b, agg2, pstat2, M_PAIRS);
    k_affine_part<<<1, 32, 0, stream>>>(pstat2, B2T, gn3_w, gn3_b, gn3_ms, invM,
                                        st + S_A3, st + S_B3);
    k_pred<<<cdiv(P_OUT, 256), 256, 0, stream>>>(agg2, pos2, st + S_A3, st + S_B3,
                                                 predW, predb, out, P_OUT);
}

// Round 10
// 1167.877 us; speedup vs baseline: 1.7932x; 1.7932x over previous
//
#include <hip/hip_runtime.h>

#define N_NODES 50000
#define E1N 1600000
#define M_PAIRS 200000
#define E2N 3200000
#define P_OUT 20000
#define EPSF 1e-5f

#define RED_BLOCKS 512
#define TB 64                  // dest-tile (bucket) size in nodes
#define B1T 782                // ceil(N_NODES/64)
#define B2T 3125               // ceil(M_PAIRS/64)
#define NBKT (B1T + B2T)       // 3907
#define PCHUNK 8192            // edges per partition block

// ---------------- stats offsets within stats buffer (floats) ----------------
#define S0_SUM   0
#define S0_SQ    32
#define S_A0     64
#define S_B0ROW  96
#define S1_SUM   128
#define S1_SQ    160
#define S_A1     192
#define S_B1     224
#define S_CNT    256   // int
#define S_ZC0    288
#define S_ZC1    320
#define S3_SUM   352
#define S3_SQ    384
#define S_A3     416
#define S_B3     448
#define S_TOTAL  512

__device__ __forceinline__ void f4add(float4& a, const float4 b) {
    a.x += b.x; a.y += b.y; a.z += b.z; a.w += b.w;
}

// block-level reduce of per-thread float4 partials (feature group = (tid&7)*4)
__device__ __forceinline__ void stats_block_reduce(float4 s, float4 q,
                                                   float* __restrict__ sum,
                                                   float* __restrict__ sumsq) {
    __shared__ float4 ss[256], sq[256];
    int tid = threadIdx.x;
    ss[tid] = s; sq[tid] = q;
    __syncthreads();
    #pragma unroll
    for (int st = 128; st >= 8; st >>= 1) {
        if (tid < st) { f4add(ss[tid], ss[tid + st]); f4add(sq[tid], sq[tid + st]); }
        __syncthreads();
    }
    if (tid < 8) {
        int base = tid * 4;
        float4 fs = ss[tid], fq = sq[tid];
        atomicAdd(&sum[base + 0], fs.x);
        atomicAdd(&sum[base + 1], fs.y);
        atomicAdd(&sum[base + 2], fs.z);
        atomicAdd(&sum[base + 3], fs.w);
        atomicAdd(&sumsq[base + 0], fq.x);
        atomicAdd(&sumsq[base + 1], fq.y);
        atomicAdd(&sumsq[base + 2], fq.z);
        atomicAdd(&sumsq[base + 3], fq.w);
    }
}

// gather embedding rows (float4 granularity), store e, accumulate gn0 stats
__global__ void k_embed_stats(const float* __restrict__ emb, const int* __restrict__ x,
                              float* __restrict__ e, float* __restrict__ sum,
                              float* __restrict__ sumsq, int n) {
    long n4 = (long)n * 8;
    float4 s = {0,0,0,0}, q = {0,0,0,0};
    float4* e4 = (float4*)e;
    long stride = (long)gridDim.x * 256;
    for (long i = (long)blockIdx.x * 256 + threadIdx.x; i < n4; i += stride) {
        int node = (int)(i >> 3), fg = ((int)i & 7) * 4;
        int xr = x[node];
        float4 v = *(const float4*)&emb[(long)xr * 32 + fg];
        e4[i] = v;
        s.x += v.x; s.y += v.y; s.z += v.z; s.w += v.w;
        q.x += v.x * v.x; q.y += v.y * v.y; q.z += v.z * v.z; q.w += v.w * v.w;
    }
    stats_block_reduce(s, q, sum, sumsq);
}

// GraphNorm -> per-feature affine A,B.  y = A*x + B
__global__ void k_affine32(const float* __restrict__ sum, const float* __restrict__ sumsq,
                           const float* __restrict__ w, const float* __restrict__ b,
                           const float* __restrict__ ms, float invN,
                           float* __restrict__ A, float* __restrict__ B) {
    int f = threadIdx.x;  // 32 threads
    float mean = sum[f] * invN;
    float c = ms[f] * mean;
    float var = sumsq[f] * invN - 2.f * c * mean + c * c;
    float rs = rsqrtf(var + EPSF);
    A[f] = w[f] * rs;
    B[f] = b[f] - w[f] * rs * c;
}

// gn0 affine + fold shift through c1_W (atomic-accumulated stats)
__global__ void k_affine_fold(const float* __restrict__ sum, const float* __restrict__ sumsq,
                              const float* __restrict__ w, const float* __restrict__ b,
                              const float* __restrict__ ms, float invN,
                              const float* __restrict__ W,
                              float* __restrict__ A, float* __restrict__ brow) {
    __shared__ float Bl[32];
    int f = threadIdx.x;  // 32 threads
    float mean = sum[f] * invN;
    float c = ms[f] * mean;
    float var = sumsq[f] * invN - 2.f * c * mean + c * c;
    float rs = rsqrtf(var + EPSF);
    A[f] = w[f] * rs;
    Bl[f] = b[f] - w[f] * rs * c;
    __syncthreads();
    float s = 0.f;
    #pragma unroll
    for (int f2 = 0; f2 < 32; f2++) s += Bl[f2] * W[f2 * 32 + f];
    brow[f] = s;
}

// parallel reduce of per-block partial stats: pstat[i*64 + 0..31]=sum, [32..63]=sq
// 32 blocks x 256 threads; coalesced row reads; 64 atomics per block at the end.
__global__ void k_pstat_reduce(const float* __restrict__ pstat, int nblk,
                               float* __restrict__ sum, float* __restrict__ sumsq) {
    int tid = threadIdx.x;
    int v = tid & 63;       // column within 64-float row
    int rep = tid >> 6;     // 0..3
    float s = 0.f;
    for (int i = blockIdx.x * 4 + rep; i < nblk; i += gridDim.x * 4)
        s += pstat[(long)i * 64 + v];
    __shared__ float sd[256];
    sd[tid] = s;
    __syncthreads();
    if (tid < 64) {
        s = sd[tid] + sd[tid + 64] + sd[tid + 128] + sd[tid + 192];
        atomicAdd((v < 32) ? &sum[v] : &sumsq[v - 32], s);
    }
}

// u[i][o] = (sum_f (A[f]*e[i][f]) * W[f][o] + brow[o]) * dscale[i]
__global__ void k_mm32s(const float* __restrict__ e, const float* __restrict__ W,
                        const float* __restrict__ A, const float* __restrict__ brow,
                        const float* __restrict__ dscale, float* __restrict__ t, int n) {
    __shared__ float Wp[32][32];
    __shared__ float rows[8][32];
    int lt = threadIdx.x;
    for (int k = lt; k < 1024; k += 256) {
        int f = k >> 5;
        Wp[f][k & 31] = A[f] * W[k];
    }
    int nl = lt >> 5, o = lt & 31;
    int node = blockIdx.x * 8 + nl;
    if (node < n) rows[nl][o] = e[(long)node * 32 + o];
    __syncthreads();
    if (node < n) {
        float acc = brow[o];
        #pragma unroll
        for (int f = 0; f < 32; f++) acc += rows[nl][f] * Wp[f][o];
        t[(long)node * 32 + o] = acc * dscale[node];
    }
}

// hw[i][o] = sum_f relu(A[f]*g[i][f]+B[f]) * W[f][o]   (fused gn1 affine+ReLU)
__global__ void k_mm32_relu_in(const float* __restrict__ g, const float* __restrict__ W,
                               const float* __restrict__ A, const float* __restrict__ B,
                               float* __restrict__ hw, int n) {
    __shared__ float Wp[32][32];
    __shared__ float rows[8][32];
    int lt = threadIdx.x;
    for (int k = lt; k < 1024; k += 256) {
        Wp[k >> 5][k & 31] = W[k];
    }
    int nl = lt >> 5, o = lt & 31;
    int node = blockIdx.x * 8 + nl;
    if (node < n) rows[nl][o] = fmaxf(A[o] * g[(long)node * 32 + o] + B[o], 0.f);
    __syncthreads();
    if (node < n) {
        float acc = 0.f;
        #pragma unroll
        for (int f = 0; f < 32; f++) acc += rows[nl][f] * Wp[f][o];
        hw[(long)node * 32 + o] = acc;
    }
}

// ---------------- binned aggregation machinery ----------------

// per-bucket edge counts (LDS histogram, one flush per block; 128 blocks)
__global__ void k_bcount(const int* __restrict__ e1col, const int* __restrict__ e2col,
                         int* __restrict__ bcnt) {
    __shared__ int hist[NBKT];
    for (int i = threadIdx.x; i < NBKT; i += 256) hist[i] = 0;
    __syncthreads();
    long total = (long)E1N + E2N;
    for (long i = (long)blockIdx.x * 256 + threadIdx.x; i < total; i += (long)gridDim.x * 256) {
        int b;
        if (i < E1N) b = e1col[i] >> 6;
        else         b = B1T + (e2col[i - E1N] >> 6);
        atomicAdd(&hist[b], 1);
    }
    __syncthreads();
    for (int i = threadIdx.x; i < NBKT; i += 256)
        if (hist[i]) atomicAdd(&bcnt[i], hist[i]);
}

// exclusive scan of bucket counts (single block, 1024 thr x 4); bbase[NBKT]=total
__global__ void k_bscan(const int* __restrict__ bcnt, int* __restrict__ bbase) {
    __shared__ int sd[1024];
    int t = threadIdx.x;
    int v[4]; int s = 0;
    #pragma unroll
    for (int u = 0; u < 4; u++) {
        int idx = t * 4 + u;
        v[u] = (idx < NBKT) ? bcnt[idx] : 0;
        s += v[u];
    }
    sd[t] = s;
    __syncthreads();
    for (int off = 1; off < 1024; off <<= 1) {
        int a = (t >= off) ? sd[t - off] : 0;
        __syncthreads();
        sd[t] += a;
        __syncthreads();
    }
    int run = sd[t] - s;
    #pragma unroll
    for (int u = 0; u < 4; u++) {
        int idx = t * 4 + u;
        if (idx <= NBKT) bbase[idx] = run;
        run += v[u];
    }
}

// partition edges into bucket-contiguous packed records (row<<6 | c_lo)
__global__ void k_partition(const int* __restrict__ row, const int* __restrict__ col,
                            int ne, int bucket0, int nbk,
                            int* __restrict__ cursor, const int* __restrict__ bbase,
                            int* __restrict__ recs) {
    __shared__ int hist[B2T];
    __shared__ int rbase[B2T];
    for (int i = threadIdx.x; i < nbk; i += 256) hist[i] = 0;
    __syncthreads();
    int c0 = blockIdx.x * PCHUNK;
    int cend = min(c0 + PCHUNK, ne);
    for (int i = c0 + threadIdx.x; i < cend; i += 256)
        atomicAdd(&hist[col[i] >> 6], 1);
    __syncthreads();
    for (int b = threadIdx.x; b < nbk; b += 256) {
        int h = hist[b];
        rbase[b] = h ? bbase[bucket0 + b] + atomicAdd(&cursor[bucket0 + b], h) : 0;
        hist[b] = 0;
    }
    __syncthreads();
    for (int i = c0 + threadIdx.x; i < cend; i += 256) {
        int c = col[i];
        int b = c >> 6;
        int rank = atomicAdd(&hist[b], 1);
        recs[rbase[b] + rank] = (row[i] << 6) | (c & 63);
    }
}

// per-node degrees -> dinv, from binned records via LDS counters
__global__ void k_deg_tiled(const int* __restrict__ recs, const int* __restrict__ bbase,
                            int bucket0, float* __restrict__ dinv, int n) {
    __shared__ int cnt[TB];
    int tid = threadIdx.x;
    if (tid < TB) cnt[tid] = 0;
    __syncthreads();
    int gb = bucket0 + blockIdx.x;
    int beg = bbase[gb], end = bbase[gb + 1];
    for (int i = beg + tid; i < end; i += 256)
        atomicAdd(&cnt[recs[i] & 63], 1);
    __syncthreads();
    int c = blockIdx.x * TB + tid;
    if (tid < TB && c < n) dinv[c] = rsqrtf((float)cnt[tid] + 1.f);
}

// tile aggregation v3: 256 thr (8 half-waves), BRANCH-FREE register unroll-8 for
// true 8-deep MLP per half-wave. LDS fp32 accumulator per 64-node dest tile.
// Epilogue fuses self-loop + bias + dinv scaling; writes per-block partial stats.
__global__ __launch_bounds__(256) void k_tile_agg(
        const int* __restrict__ recs, const int* __restrict__ bbase, int bucket0,
        const float* __restrict__ u, const float* __restrict__ dinv,
        const float* __restrict__ bias, float* __restrict__ aggout,
        float* __restrict__ pstat, int n) {
    __shared__ float acc[TB][32];   // 8 KB
    int tid = threadIdx.x;
    float4* a4 = (float4*)&acc[0][0];
    for (int i = tid; i < TB * 8; i += 256) a4[i] = make_float4(0.f, 0.f, 0.f, 0.f);
    __syncthreads();
    int gb = bucket0 + blockIdx.x;
    int beg = bbase[gb], end = bbase[gb + 1];
    int hwid = tid >> 5;        // half-wave id 0..7
    int f = tid & 31;
    int cnt = end - beg;
    int nfull = cnt & ~63;      // multiple of 64
    const float* uf = u + f;
    // main loop: branch-free, 8 independent record streams per half-wave
    for (int base = beg + hwid * 8; base < beg + nfull; base += 64) {
        int r0 = recs[base + 0];
        int r1 = recs[base + 1];
        int r2 = recs[base + 2];
        int r3 = recs[base + 3];
        int r4 = recs[base + 4];
        int r5 = recs[base + 5];
        int r6 = recs[base + 6];
        int r7 = recs[base + 7];
        float v0 = uf[(long)(r0 >> 6) * 32];
        float v1 = uf[(long)(r1 >> 6) * 32];
        float v2 = uf[(long)(r2 >> 6) * 32];
        float v3 = uf[(long)(r3 >> 6) * 32];
        float v4 = uf[(long)(r4 >> 6) * 32];
        float v5 = uf[(long)(r5 >> 6) * 32];
        float v6 = uf[(long)(r6 >> 6) * 32];
        float v7 = uf[(long)(r7 >> 6) * 32];
        atomicAdd(&acc[r0 & 63][f], v0);
        atomicAdd(&acc[r1 & 63][f], v1);
        atomicAdd(&acc[r2 & 63][f], v2);
        atomicAdd(&acc[r3 & 63][f], v3);
        atomicAdd(&acc[r4 & 63][f], v4);
        atomicAdd(&acc[r5 & 63][f], v5);
        atomicAdd(&acc[r6 & 63][f], v6);
        atomicAdd(&acc[r7 & 63][f], v7);
    }
    // tail (< 64 records)
    for (int i = beg + nfull + hwid; i < end; i += 8) {
        int rec = recs[i];
        atomicAdd(&acc[rec & 63][f], uf[(long)(rec >> 6) * 32]);
    }
    __syncthreads();
    float sacc = 0.f, qacc = 0.f;
    int tile0 = blockIdx.x * TB;
    float bf = bias[f];
    for (int rw = hwid; rw < TB; rw += 8) {
        int c = tile0 + rw;
        if (c < n) {
            float dc = dinv[c];
            float a = dc * (acc[rw][f] + u[(long)c * 32 + f]) + bf;
            aggout[(long)c * 32 + f] = a;
            sacc += a;
            qacc += a * a;
        }
    }
    __syncthreads();
    float* red = &acc[0][0];
    red[tid] = sacc;
    __syncthreads();
    if (tid < 32) {
        float s = 0.f;
        #pragma unroll
        for (int k = 0; k < 8; k++) s += red[tid + k * 32];
        pstat[(long)blockIdx.x * 64 + tid] = s;
    }
    __syncthreads();
    red[tid] = qacc;
    __syncthreads();
    if (tid < 32) {
        float q = 0.f;
        #pragma unroll
        for (int k = 0; k < 8; k++) q += red[tid + k * 32];
        pstat[(long)blockIdx.x * 64 + 32 + tid] = q;
    }
}

__global__ void k_mask(const int* __restrict__ pos2, int* __restrict__ mask, int p) {
    int i = blockIdx.x * 256 + threadIdx.x;
    if (i < p) mask[pos2[i]] = 1;
}

__global__ void k_maskcnt(const int* __restrict__ mask, int* __restrict__ cnt, int m) {
    __shared__ int sd[256];
    int idx = blockIdx.x * 256 + threadIdx.x;
    sd[threadIdx.x] = (idx < m) ? mask[idx] : 0;
    __syncthreads();
    for (int s = 128; s > 0; s >>= 1) {
        if (threadIdx.x < s) sd[threadIdx.x] += sd[threadIdx.x + s];
        __syncthreads();
    }
    if (threadIdx.x == 0) atomicAdd(cnt, sd[0]);
}

// z has only two distinct rows (mask 0/1); zc{0,1}[o] = z{0,1} @ c2_W[32:48]
__global__ void k_zcalc(const float* __restrict__ emb2, const float* __restrict__ w,
                        const float* __restrict__ b, const float* __restrict__ ms,
                        const int* __restrict__ cnt, const float* __restrict__ c2W,
                        float* __restrict__ zc0, float* __restrict__ zc1) {
    __shared__ float z0[16], z1[16];
    int t = threadIdx.x;  // 32 threads
    const float Mf = (float)M_PAIRS;
    if (t < 16) {
        float e0 = emb2[t], e1 = emb2[16 + t];
        float c1f = (float)(*cnt);
        float mean = (c1f * e1 + (Mf - c1f) * e0) / Mf;
        float c = ms[t] * mean;
        float d0 = e0 - c, d1 = e1 - c;
        float var = (c1f * d1 * d1 + (Mf - c1f) * d0 * d0) / Mf;
        float rs = rsqrtf(var + EPSF);
        z0[t] = w[t] * d0 * rs + b[t];
        z1[t] = w[t] * d1 * rs + b[t];
    }
    __syncthreads();
    float s0 = 0.f, s1 = 0.f;
    #pragma unroll
    for (int f = 0; f < 16; f++) {
        float wv = c2W[(32 + f) * 32 + t];
        s0 += z0[f] * wv;
        s1 += z1[f] * wv;
    }
    zc0[t] = s0;
    zc1[t] = s1;
}

// t2[j][fg..] = (hw[a][fg..] + hw[b][fg..] + zc_{mask[j]}[fg..]) * d2[j]
__global__ void k_t2(const float* __restrict__ hw, const int* __restrict__ pos1,
                     const int* __restrict__ mask, const float* __restrict__ zc0,
                     const float* __restrict__ zc1, const float* __restrict__ d2,
                     float* __restrict__ t2, int m) {
    long idx = (long)blockIdx.x * 256 + threadIdx.x;
    if (idx >= (long)m * 8) return;
    int j = (int)(idx >> 3), fg = ((int)idx & 7) * 4;
    int a = pos1[2 * j], b = pos1[2 * j + 1];
    const float* zc = mask[j] ? zc1 : zc0;
    float dj = d2[j];
    float4 va = *(const float4*)&hw[(long)a * 32 + fg];
    float4 vb = *(const float4*)&hw[(long)b * 32 + fg];
    float4 vz = *(const float4*)&zc[fg];
    float4 r;
    r.x = (va.x + vb.x + vz.x) * dj;
    r.y = (va.y + vb.y + vz.y) * dj;
    r.z = (va.z + vb.z + vz.z) * dj;
    r.w = (va.w + vb.w + vz.w) * dj;
    *(float4*)&t2[idx * 4] = r;
}

// out[k] = relu(A*g2[pos2[k]]+B) . predW + predb
__global__ void k_pred(const float* __restrict__ g2, const int* __restrict__ pos2,
                       const float* __restrict__ A, const float* __restrict__ B,
                       const float* __restrict__ predW, const float* __restrict__ predb,
                       float* __restrict__ out, int p) {
    int k = blockIdx.x * 256 + threadIdx.x;
    if (k >= p) return;
    int j = pos2[k];
    float s = predb[0];
    #pragma unroll
    for (int o = 0; o < 32; o++)
        s += fmaxf(A[o] * g2[(long)j * 32 + o] + B[o], 0.f) * predW[o];
    out[k] = s;
}

extern "C" void kernel_launch(void* const* d_in, const int* in_sizes, int n_in,
                              void* d_out, int out_size, void* d_ws, size_t ws_size,
                              hipStream_t stream) {
    const int*   x      = (const int*)d_in[0];
    const int*   e1row  = (const int*)d_in[1];
    const int*   e1col  = e1row + E1N;
    const int*   e2row  = (const int*)d_in[2];
    const int*   e2col  = e2row + E2N;
    const int*   pos1   = (const int*)d_in[3];
    const int*   pos2   = (const int*)d_in[4];
    const float* emb1   = (const float*)d_in[5];
    const float* gn0_w  = (const float*)d_in[6];
    const float* gn0_b  = (const float*)d_in[7];
    const float* gn0_ms = (const float*)d_in[8];
    const float* c1_W   = (const float*)d_in[9];
    const float* c1_b   = (const float*)d_in[10];
    const float* gn1_w  = (const float*)d_in[11];
    const float* gn1_b  = (const float*)d_in[12];
    const float* gn1_ms = (const float*)d_in[13];
    const float* emb2   = (const float*)d_in[14];
    const float* gn2_w  = (const float*)d_in[15];
    const float* gn2_b  = (const float*)d_in[16];
    const float* gn2_ms = (const float*)d_in[17];
    const float* c2_W   = (const float*)d_in[18];
    const float* c2_b   = (const float*)d_in[19];
    const float* gn3_w  = (const float*)d_in[20];
    const float* gn3_b  = (const float*)d_in[21];
    const float* gn3_ms = (const float*)d_in[22];
    const float* predW  = (const float*)d_in[23];
    const float* predb  = (const float*)d_in[24];
    float* out = (float*)d_out;

    // ---------------- workspace arena (floats) ----------------
    const size_t N32 = (size_t)N_NODES * 32;
    const size_t M32 = (size_t)M_PAIRS * 32;
    float* fw = (float*)d_ws;
    size_t off = 0;
    auto alloc = [&](size_t n) { float* p = fw + off; off += n; return p; };
    float* e      = alloc(N32);               // alias hw later
    float* t      = alloc(N32);               // u1 = gn0(e)@W * dinv
    float* agg    = alloc(N32);
    float* t2     = alloc(M32);               // u2
    float* agg2   = alloc(M32);
    int*   recs   = (int*)alloc((size_t)E1N + E2N);
    float* d1     = alloc(N_NODES);
    float* d2     = alloc(M_PAIRS);
    int*   bbase  = (int*)alloc(NBKT + 2);
    float* pstat1 = alloc((size_t)B1T * 64);
    float* pstat2 = alloc((size_t)B2T * 64);
    // ---- zero region (single memset): bcnt, cursor, mask, stats ----
    int*   bcnt   = (int*)alloc(NBKT + 2);
    int*   cursor = (int*)alloc(NBKT + 2);
    int*   mask   = (int*)alloc(M_PAIRS);
    float* st     = alloc(S_TOTAL);
    float* hw     = e;  // alias: e dead after k_mm32s

    const size_t zero_bytes = (2 * (size_t)(NBKT + 2) + (size_t)M_PAIRS + S_TOTAL) * 4;
    hipMemsetAsync(bcnt, 0, zero_bytes, stream);

    auto cdiv = [](long a, long b) { return (int)((a + b - 1) / b); };
    const float invN = 1.f / (float)N_NODES;
    const float invM = 1.f / (float)M_PAIRS;

    // ---- bin both edge lists by dest tile ----
    k_bcount<<<128, 256, 0, stream>>>(e1col, e2col, bcnt);
    k_bscan<<<1, 1024, 0, stream>>>(bcnt, bbase);
    k_partition<<<cdiv(E1N, PCHUNK), 256, 0, stream>>>(e1row, e1col, E1N, 0,   B1T, cursor, bbase, recs);
    k_partition<<<cdiv(E2N, PCHUNK), 256, 0, stream>>>(e2row, e2col, E2N, B1T, B2T, cursor, bbase, recs);
    k_deg_tiled<<<B1T, 256, 0, stream>>>(recs, bbase, 0,   d1, N_NODES);
    k_deg_tiled<<<B2T, 256, 0, stream>>>(recs, bbase, B1T, d2, M_PAIRS);

    // ---- stage 0: embedding + gn0 stats ----
    k_embed_stats<<<RED_BLOCKS, 256, 0, stream>>>(emb1, x, e, st + S0_SUM, st + S0_SQ, N_NODES);
    k_affine_fold<<<1, 32, 0, stream>>>(st + S0_SUM, st + S0_SQ, gn0_w, gn0_b, gn0_ms, invN,
                                        c1_W, st + S_A0, st + S_B0ROW);

    // ---- conv1: u1 = (gn0(e) @ c1_W) * d1 ; tile aggregation (+gn1 partial stats) ----
    k_mm32s<<<cdiv(N_NODES, 8), 256, 0, stream>>>(e, c1_W, st + S_A0, st + S_B0ROW, d1, t, N_NODES);
    k_tile_agg<<<B1T, 256, 0, stream>>>(recs, bbase, 0, t, d1, c1_b, agg, pstat1, N_NODES);
    k_pstat_reduce<<<32, 256, 0, stream>>>(pstat1, B1T, st + S1_SUM, st + S1_SQ);
    k_affine32<<<1, 32, 0, stream>>>(st + S1_SUM, st + S1_SQ, gn1_w, gn1_b, gn1_ms, invN,
                                     st + S_A1, st + S_B1);
    k_mm32_relu_in<<<cdiv(N_NODES, 8), 256, 0, stream>>>(agg, c2_W, st + S_A1, st + S_B1,
                                                         hw, N_NODES);

    // ---- mask / z path ----
    k_mask<<<cdiv(P_OUT, 256), 256, 0, stream>>>(pos2, mask, P_OUT);
    k_maskcnt<<<cdiv(M_PAIRS, 256), 256, 0, stream>>>(mask, (int*)(st + S_CNT), M_PAIRS);
    k_zcalc<<<1, 32, 0, stream>>>(emb2, gn2_w, gn2_b, gn2_ms, (const int*)(st + S_CNT),
                                  c2_W, st + S_ZC0, st + S_ZC1);

    // ---- conv2: u2 = (hw[a]+hw[b]+zc) * d2 ; tile aggregation (+gn3 partial stats) ----
    k_t2<<<cdiv((long)M_PAIRS * 8, 256), 256, 0, stream>>>(hw, pos1, mask, st + S_ZC0,
                                                           st + S_ZC1, d2, t2, M_PAIRS);
    k_tile_agg<<<B2T, 256, 0, stream>>>(recs, bbase, B1T, t2, d2, c2_b, agg2, pstat2, M_PAIRS);
    k_pstat_reduce<<<32, 256, 0, stream>>>(pstat2, B2T, st + S3_SUM, st + S3_SQ);
    k_affine32<<<1, 32, 0, stream>>>(st + S3_SUM, st + S3_SQ, gn3_w, gn3_b, gn3_ms, invM,
                                     st + S_A3, st + S_B3);
    k_pred<<<cdiv(P_OUT, 256), 256, 0, stream>>>(agg2, pos2, st + S_A3, st + S_B3,
                                                 predW, predb, out, P_OUT);
}

// Round 11
// 946.450 us; speedup vs baseline: 2.2127x; 1.2340x over previous
//
#include <hip/hip_runtime.h>

#define N_NODES 50000
#define E1N 1600000
#define M_PAIRS 200000
#define E2N 3200000
#define P_OUT 20000
#define EPSF 1e-5f

#define RED_BLOCKS 512

// ---------------- stats offsets within stats buffer (floats) ----------------
#define S0_SUM   0
#define S0_SQ    32
#define S_A0     64
#define S_B0ROW  96
#define S1_SUM   128
#define S1_SQ    160
#define S_A1     192
#define S_B1     224
#define S_CNT    256   // int
#define S_ZC0    288
#define S_ZC1    320
#define S3_SUM   352
#define S3_SQ    384
#define S_A3     416
#define S_B3     448
#define S_TOTAL  512

__device__ __forceinline__ void f4add(float4& a, const float4 b) {
    a.x += b.x; a.y += b.y; a.z += b.z; a.w += b.w;
}

// block-level reduce of per-thread float4 partials (feature group = (tid&7)*4)
__device__ __forceinline__ void stats_block_reduce(float4 s, float4 q,
                                                   float* __restrict__ sum,
                                                   float* __restrict__ sumsq) {
    __shared__ float4 ss[256], sq[256];
    int tid = threadIdx.x;
    ss[tid] = s; sq[tid] = q;
    __syncthreads();
    #pragma unroll
    for (int st = 128; st >= 8; st >>= 1) {
        if (tid < st) { f4add(ss[tid], ss[tid + st]); f4add(sq[tid], sq[tid + st]); }
        __syncthreads();
    }
    if (tid < 8) {
        int base = tid * 4;
        float4 fs = ss[tid], fq = sq[tid];
        atomicAdd(&sum[base + 0], fs.x);
        atomicAdd(&sum[base + 1], fs.y);
        atomicAdd(&sum[base + 2], fs.z);
        atomicAdd(&sum[base + 3], fs.w);
        atomicAdd(&sumsq[base + 0], fq.x);
        atomicAdd(&sumsq[base + 1], fq.y);
        atomicAdd(&sumsq[base + 2], fq.z);
        atomicAdd(&sumsq[base + 3], fq.w);
    }
}

// gather embedding rows (float4 granularity), store e, accumulate gn0 stats
__global__ void k_embed_stats(const float* __restrict__ emb, const int* __restrict__ x,
                              float* __restrict__ e, float* __restrict__ sum,
                              float* __restrict__ sumsq, int n) {
    long n4 = (long)n * 8;
    float4 s = {0,0,0,0}, q = {0,0,0,0};
    float4* e4 = (float4*)e;
    long stride = (long)gridDim.x * 256;
    for (long i = (long)blockIdx.x * 256 + threadIdx.x; i < n4; i += stride) {
        int node = (int)(i >> 3), fg = ((int)i & 7) * 4;
        int xr = x[node];
        float4 v = *(const float4*)&emb[(long)xr * 32 + fg];
        e4[i] = v;
        s.x += v.x; s.y += v.y; s.z += v.z; s.w += v.w;
        q.x += v.x * v.x; q.y += v.y * v.y; q.z += v.z * v.z; q.w += v.w * v.w;
    }
    stats_block_reduce(s, q, sum, sumsq);
}

// GraphNorm -> per-feature affine A,B.  y = A*x + B
__global__ void k_affine32(const float* __restrict__ sum, const float* __restrict__ sumsq,
                           const float* __restrict__ w, const float* __restrict__ b,
                           const float* __restrict__ ms, float invN,
                           float* __restrict__ A, float* __restrict__ B) {
    int f = threadIdx.x;  // 32 threads
    float mean = sum[f] * invN;
    float c = ms[f] * mean;
    float var = sumsq[f] * invN - 2.f * c * mean + c * c;
    float rs = rsqrtf(var + EPSF);
    A[f] = w[f] * rs;
    B[f] = b[f] - w[f] * rs * c;
}

// gn0 affine + fold shift through c1_W:  A[f], brow[o] = sum_f B[f]*W[f][o]
__global__ void k_affine_fold(const float* __restrict__ sum, const float* __restrict__ sumsq,
                              const float* __restrict__ w, const float* __restrict__ b,
                              const float* __restrict__ ms, float invN,
                              const float* __restrict__ W,
                              float* __restrict__ A, float* __restrict__ brow) {
    __shared__ float Bl[32];
    int f = threadIdx.x;  // 32 threads
    float mean = sum[f] * invN;
    float c = ms[f] * mean;
    float var = sumsq[f] * invN - 2.f * c * mean + c * c;
    float rs = rsqrtf(var + EPSF);
    A[f] = w[f] * rs;
    Bl[f] = b[f] - w[f] * rs * c;
    __syncthreads();
    float s = 0.f;
    #pragma unroll
    for (int f2 = 0; f2 < 32; f2++) s += Bl[f2] * W[f2 * 32 + f];
    brow[f] = s;
}

// u[i][o] = (sum_f (A[f]*e[i][f]) * W[f][o] + brow[o]) * dscale[i]
__global__ void k_mm32s(const float* __restrict__ e, const float* __restrict__ W,
                        const float* __restrict__ A, const float* __restrict__ brow,
                        const float* __restrict__ dscale, float* __restrict__ t, int n) {
    __shared__ float Wp[32][32];
    __shared__ float rows[8][32];
    int lt = threadIdx.x;
    for (int k = lt; k < 1024; k += 256) {
        int f = k >> 5;
        Wp[f][k & 31] = A[f] * W[k];
    }
    int nl = lt >> 5, o = lt & 31;
    int node = blockIdx.x * 8 + nl;
    if (node < n) rows[nl][o] = e[(long)node * 32 + o];
    __syncthreads();
    if (node < n) {
        float acc = brow[o];
        #pragma unroll
        for (int f = 0; f < 32; f++) acc += rows[nl][f] * Wp[f][o];
        t[(long)node * 32 + o] = acc * dscale[node];
    }
}

// hw[i][o] = sum_f relu(A[f]*g[i][f]+B[f]) * W[f][o]   (fused gn1 affine+ReLU)
__global__ void k_mm32_relu_in(const float* __restrict__ g, const float* __restrict__ W,
                               const float* __restrict__ A, const float* __restrict__ B,
                               float* __restrict__ hw, int n) {
    __shared__ float Wp[32][32];
    __shared__ float rows[8][32];
    int lt = threadIdx.x;
    for (int k = lt; k < 1024; k += 256) {
        Wp[k >> 5][k & 31] = W[k];
    }
    int nl = lt >> 5, o = lt & 31;
    int node = blockIdx.x * 8 + nl;
    if (node < n) rows[nl][o] = fmaxf(A[o] * g[(long)node * 32 + o] + B[o], 0.f);
    __syncthreads();
    if (node < n) {
        float acc = 0.f;
        #pragma unroll
        for (int f = 0; f < 32; f++) acc += rows[nl][f] * Wp[f][o];
        hw[(long)node * 32 + o] = acc;
    }
}

// degrees for both graphs (float counts)
__global__ void k_deg_all(const int* __restrict__ e1col, const int* __restrict__ e2col,
                          float* __restrict__ d1, float* __restrict__ d2) {
    long i = (long)blockIdx.x * 256 + threadIdx.x;
    if (i < E1N) atomicAdd(&d1[e1col[i]], 1.f);
    else if (i - E1N < E2N) atomicAdd(&d2[e2col[i - E1N]], 1.f);
}

__global__ void k_dinv_all(float* __restrict__ d1, float* __restrict__ d2) {
    int i = blockIdx.x * 256 + threadIdx.x;
    if (i < N_NODES) d1[i] = rsqrtf(d1[i] + 1.f);
    else if (i - N_NODES < M_PAIRS) {
        int j = i - N_NODES;
        d2[j] = rsqrtf(d2[j] + 1.f);
    }
}

// coalesced atomic scatter: agg[col][f] += u[row][f]
// one thread per (edge, feature): 32 consecutive lanes -> one dest row
__global__ void k_scatter(const int* __restrict__ row, const int* __restrict__ col,
                          const float* __restrict__ u, float* __restrict__ agg, int ne) {
    long idx = (long)blockIdx.x * 256 + threadIdx.x;
    if (idx >= (long)ne * 32) return;
    int e = (int)(idx >> 5), f = (int)idx & 31;
    atomicAdd(&agg[(long)col[e] * 32 + f], u[(long)row[e] * 32 + f]);
}

// epilogue: agg = dinv[i]*(agg + u) + bias, fused GraphNorm stats accumulation
__global__ void k_selfbias_stats(float* __restrict__ agg, const float* __restrict__ u,
                                 const float* __restrict__ dinv, const float* __restrict__ bias,
                                 float* __restrict__ sum, float* __restrict__ sumsq, int n) {
    long n4 = (long)n * 8;
    float4 s = {0,0,0,0}, q = {0,0,0,0};
    float4* a4 = (float4*)agg;
    const float4* u4 = (const float4*)u;
    long stride = (long)gridDim.x * 256;
    for (long idx = (long)blockIdx.x * 256 + threadIdx.x; idx < n4; idx += stride) {
        int i = (int)(idx >> 3), fg = ((int)idx & 7) * 4;
        float dc = dinv[i];
        float4 a = a4[idx];
        float4 uv = u4[idx];
        float4 b = *(const float4*)&bias[fg];
        float4 r;
        r.x = dc * (a.x + uv.x) + b.x;
        r.y = dc * (a.y + uv.y) + b.y;
        r.z = dc * (a.z + uv.z) + b.z;
        r.w = dc * (a.w + uv.w) + b.w;
        a4[idx] = r;
        s.x += r.x; s.y += r.y; s.z += r.z; s.w += r.w;
        q.x += r.x * r.x; q.y += r.y * r.y; q.z += r.z * r.z; q.w += r.w * r.w;
    }
    stats_block_reduce(s, q, sum, sumsq);
}

__global__ void k_mask(const int* __restrict__ pos2, int* __restrict__ mask, int p) {
    int i = blockIdx.x * 256 + threadIdx.x;
    if (i < p) mask[pos2[i]] = 1;
}

__global__ void k_maskcnt(const int* __restrict__ mask, int* __restrict__ cnt, int m) {
    __shared__ int sd[256];
    int idx = blockIdx.x * 256 + threadIdx.x;
    sd[threadIdx.x] = (idx < m) ? mask[idx] : 0;
    __syncthreads();
    for (int s = 128; s > 0; s >>= 1) {
        if (threadIdx.x < s) sd[threadIdx.x] += sd[threadIdx.x + s];
        __syncthreads();
    }
    if (threadIdx.x == 0) atomicAdd(cnt, sd[0]);
}

// z has only two distinct rows (mask 0/1); zc{0,1}[o] = z{0,1} @ c2_W[32:48]
__global__ void k_zcalc(const float* __restrict__ emb2, const float* __restrict__ w,
                        const float* __restrict__ b, const float* __restrict__ ms,
                        const int* __restrict__ cnt, const float* __restrict__ c2W,
                        float* __restrict__ zc0, float* __restrict__ zc1) {
    __shared__ float z0[16], z1[16];
    int t = threadIdx.x;  // 32 threads
    const float Mf = (float)M_PAIRS;
    if (t < 16) {
        float e0 = emb2[t], e1 = emb2[16 + t];
        float c1f = (float)(*cnt);
        float mean = (c1f * e1 + (Mf - c1f) * e0) / Mf;
        float c = ms[t] * mean;
        float d0 = e0 - c, d1 = e1 - c;
        float var = (c1f * d1 * d1 + (Mf - c1f) * d0 * d0) / Mf;
        float rs = rsqrtf(var + EPSF);
        z0[t] = w[t] * d0 * rs + b[t];
        z1[t] = w[t] * d1 * rs + b[t];
    }
    __syncthreads();
    float s0 = 0.f, s1 = 0.f;
    #pragma unroll
    for (int f = 0; f < 16; f++) {
        float wv = c2W[(32 + f) * 32 + t];
        s0 += z0[f] * wv;
        s1 += z1[f] * wv;
    }
    zc0[t] = s0;
    zc1[t] = s1;
}

// t2[j][fg..] = (hw[a][fg..] + hw[b][fg..] + zc_{mask[j]}[fg..]) * d2[j]
__global__ void k_t2(const float* __restrict__ hw, const int* __restrict__ pos1,
                     const int* __restrict__ mask, const float* __restrict__ zc0,
                     const float* __restrict__ zc1, const float* __restrict__ d2,
                     float* __restrict__ t2, int m) {
    long idx = (long)blockIdx.x * 256 + threadIdx.x;
    if (idx >= (long)m * 8) return;
    int j = (int)(idx >> 3), fg = ((int)idx & 7) * 4;
    int a = pos1[2 * j], b = pos1[2 * j + 1];
    const float* zc = mask[j] ? zc1 : zc0;
    float dj = d2[j];
    float4 va = *(const float4*)&hw[(long)a * 32 + fg];
    float4 vb = *(const float4*)&hw[(long)b * 32 + fg];
    float4 vz = *(const float4*)&zc[fg];
    float4 r;
    r.x = (va.x + vb.x + vz.x) * dj;
    r.y = (va.y + vb.y + vz.y) * dj;
    r.z = (va.z + vb.z + vz.z) * dj;
    r.w = (va.w + vb.w + vz.w) * dj;
    *(float4*)&t2[idx * 4] = r;
}

// out[k] = relu(A*g2[pos2[k]]+B) . predW + predb
__global__ void k_pred(const float* __restrict__ g2, const int* __restrict__ pos2,
                       const float* __restrict__ A, const float* __restrict__ B,
                       const float* __restrict__ predW, const float* __restrict__ predb,
                       float* __restrict__ out, int p) {
    int k = blockIdx.x * 256 + threadIdx.x;
    if (k >= p) return;
    int j = pos2[k];
    float s = predb[0];
    #pragma unroll
    for (int o = 0; o < 32; o++)
        s += fmaxf(A[o] * g2[(long)j * 32 + o] + B[o], 0.f) * predW[o];
    out[k] = s;
}

extern "C" void kernel_launch(void* const* d_in, const int* in_sizes, int n_in,
                              void* d_out, int out_size, void* d_ws, size_t ws_size,
                              hipStream_t stream) {
    const int*   x      = (const int*)d_in[0];
    const int*   e1row  = (const int*)d_in[1];
    const int*   e1col  = e1row + E1N;
    const int*   e2row  = (const int*)d_in[2];
    const int*   e2col  = e2row + E2N;
    const int*   pos1   = (const int*)d_in[3];
    const int*   pos2   = (const int*)d_in[4];
    const float* emb1   = (const float*)d_in[5];
    const float* gn0_w  = (const float*)d_in[6];
    const float* gn0_b  = (const float*)d_in[7];
    const float* gn0_ms = (const float*)d_in[8];
    const float* c1_W   = (const float*)d_in[9];
    const float* c1_b   = (const float*)d_in[10];
    const float* gn1_w  = (const float*)d_in[11];
    const float* gn1_b  = (const float*)d_in[12];
    const float* gn1_ms = (const float*)d_in[13];
    const float* emb2   = (const float*)d_in[14];
    const float* gn2_w  = (const float*)d_in[15];
    const float* gn2_b  = (const float*)d_in[16];
    const float* gn2_ms = (const float*)d_in[17];
    const float* c2_W   = (const float*)d_in[18];
    const float* c2_b   = (const float*)d_in[19];
    const float* gn3_w  = (const float*)d_in[20];
    const float* gn3_b  = (const float*)d_in[21];
    const float* gn3_ms = (const float*)d_in[22];
    const float* predW  = (const float*)d_in[23];
    const float* predb  = (const float*)d_in[24];
    float* out = (float*)d_out;

    // ---------------- workspace arena (floats) ----------------
    const size_t N32 = (size_t)N_NODES * 32;
    const size_t M32 = (size_t)M_PAIRS * 32;
    float* fw = (float*)d_ws;
    size_t off = 0;
    auto alloc = [&](size_t n) { float* p = fw + off; off += n; return p; };
    float* e    = alloc(N32);               // alias hw later
    float* t    = alloc(N32);               // u1 = (gn0(e)@W + brow) * d1
    float* t2   = alloc(M32);               // u2
    // ---- contiguous zero region ----
    float* agg  = alloc(N32);
    float* agg2 = alloc(M32);
    float* d1   = alloc(N_NODES);
    float* d2   = alloc(M_PAIRS);
    int*   mask = (int*)alloc(M_PAIRS);
    float* st   = alloc(S_TOTAL);
    float* hw   = e;  // alias: e dead after k_mm32s

    const size_t zero_bytes = (N32 + M32 + (size_t)N_NODES + 2 * (size_t)M_PAIRS + S_TOTAL) * 4;
    hipMemsetAsync(agg, 0, zero_bytes, stream);

    auto cdiv = [](long a, long b) { return (int)((a + b - 1) / b); };
    const float invN = 1.f / (float)N_NODES;
    const float invM = 1.f / (float)M_PAIRS;

    // ---- degrees for both graphs ----
    k_deg_all<<<cdiv((long)E1N + E2N, 256), 256, 0, stream>>>(e1col, e2col, d1, d2);
    k_dinv_all<<<cdiv((long)N_NODES + M_PAIRS, 256), 256, 0, stream>>>(d1, d2);

    // ---- stage 0: embedding + gn0 stats ----
    k_embed_stats<<<RED_BLOCKS, 256, 0, stream>>>(emb1, x, e, st + S0_SUM, st + S0_SQ, N_NODES);
    k_affine_fold<<<1, 32, 0, stream>>>(st + S0_SUM, st + S0_SQ, gn0_w, gn0_b, gn0_ms, invN,
                                        c1_W, st + S_A0, st + S_B0ROW);

    // ---- conv1: u1 = (gn0(e) @ c1_W) * d1 ; scatter ; epilogue+gn1 stats ----
    k_mm32s<<<cdiv(N_NODES, 8), 256, 0, stream>>>(e, c1_W, st + S_A0, st + S_B0ROW, d1, t, N_NODES);
    k_scatter<<<cdiv((long)E1N * 32, 256), 256, 0, stream>>>(e1row, e1col, t, agg, E1N);
    k_selfbias_stats<<<RED_BLOCKS, 256, 0, stream>>>(agg, t, d1, c1_b,
                                                     st + S1_SUM, st + S1_SQ, N_NODES);
    k_affine32<<<1, 32, 0, stream>>>(st + S1_SUM, st + S1_SQ, gn1_w, gn1_b, gn1_ms, invN,
                                     st + S_A1, st + S_B1);
    k_mm32_relu_in<<<cdiv(N_NODES, 8), 256, 0, stream>>>(agg, c2_W, st + S_A1, st + S_B1,
                                                         hw, N_NODES);

    // ---- mask / z path ----
    k_mask<<<cdiv(P_OUT, 256), 256, 0, stream>>>(pos2, mask, P_OUT);
    k_maskcnt<<<cdiv(M_PAIRS, 256), 256, 0, stream>>>(mask, (int*)(st + S_CNT), M_PAIRS);
    k_zcalc<<<1, 32, 0, stream>>>(emb2, gn2_w, gn2_b, gn2_ms, (const int*)(st + S_CNT),
                                  c2_W, st + S_ZC0, st + S_ZC1);

    // ---- conv2: u2 = (hw[a]+hw[b]+zc) * d2 ; scatter ; epilogue+gn3 stats ----
    k_t2<<<cdiv((long)M_PAIRS * 8, 256), 256, 0, stream>>>(hw, pos1, mask, st + S_ZC0,
                                                           st + S_ZC1, d2, t2, M_PAIRS);
    k_scatter<<<cdiv((long)E2N * 32, 256), 256, 0, stream>>>(e2row, e2col, t2, agg2, E2N);
    k_selfbias_stats<<<RED_BLOCKS, 256, 0, stream>>>(agg2, t2, d2, c2_b,
                                                     st + S3_SUM, st + S3_SQ, M_PAIRS);
    k_affine32<<<1, 32, 0, stream>>>(st + S3_SUM, st + S3_SQ, gn3_w, gn3_b, gn3_ms, invM,
                                     st + S_A3, st + S_B3);
    k_pred<<<cdiv(P_OUT, 256), 256, 0, stream>>>(agg2, pos2, st + S_A3, st + S_B3,
                                                 predW, predb, out, P_OUT);
}

// Round 12
// 877.663 us; speedup vs baseline: 2.3861x; 1.0784x over previous
//
#include <hip/hip_runtime.h>

#define N_NODES 50000
#define E1N 1600000
#define M_PAIRS 200000
#define E2N 3200000
#define P_OUT 20000
#define EPSF 1e-5f

#define RED_BLOCKS 512
#define RANGE 16384            // histogram counters per block (64 KB LDS)
#define NR1 4                  // ceil(N_NODES/RANGE)
#define NR2 13                 // ceil(M_PAIRS/RANGE)
#define BPG 32                 // blocks per range-group

// ---------------- stats offsets within stats buffer (floats) ----------------
#define S0_SUM   0
#define S0_SQ    32
#define S_A0     64
#define S_B0ROW  96
#define S1_SUM   128
#define S1_SQ    160
#define S_A1     192
#define S_B1     224
#define S_CNT    256   // int
#define S_ZC0    288
#define S_ZC1    320
#define S3_SUM   352
#define S3_SQ    384
#define S_A3     416
#define S_B3     448
#define S_TOTAL  512

__device__ __forceinline__ void f4add(float4& a, const float4 b) {
    a.x += b.x; a.y += b.y; a.z += b.z; a.w += b.w;
}

// block-level reduce of per-thread float4 partials (feature group = (tid&7)*4)
__device__ __forceinline__ void stats_block_reduce(float4 s, float4 q,
                                                   float* __restrict__ sum,
                                                   float* __restrict__ sumsq) {
    __shared__ float4 ss[256], sq[256];
    int tid = threadIdx.x;
    ss[tid] = s; sq[tid] = q;
    __syncthreads();
    #pragma unroll
    for (int st = 128; st >= 8; st >>= 1) {
        if (tid < st) { f4add(ss[tid], ss[tid + st]); f4add(sq[tid], sq[tid + st]); }
        __syncthreads();
    }
    if (tid < 8) {
        int base = tid * 4;
        float4 fs = ss[tid], fq = sq[tid];
        atomicAdd(&sum[base + 0], fs.x);
        atomicAdd(&sum[base + 1], fs.y);
        atomicAdd(&sum[base + 2], fs.z);
        atomicAdd(&sum[base + 3], fs.w);
        atomicAdd(&sumsq[base + 0], fq.x);
        atomicAdd(&sumsq[base + 1], fq.y);
        atomicAdd(&sumsq[base + 2], fq.z);
        atomicAdd(&sumsq[base + 3], fq.w);
    }
}

// gather embedding rows (float4 granularity), store e, accumulate gn0 stats
__global__ void k_embed_stats(const float* __restrict__ emb, const int* __restrict__ x,
                              float* __restrict__ e, float* __restrict__ sum,
                              float* __restrict__ sumsq, int n) {
    long n4 = (long)n * 8;
    float4 s = {0,0,0,0}, q = {0,0,0,0};
    float4* e4 = (float4*)e;
    long stride = (long)gridDim.x * 256;
    for (long i = (long)blockIdx.x * 256 + threadIdx.x; i < n4; i += stride) {
        int node = (int)(i >> 3), fg = ((int)i & 7) * 4;
        int xr = x[node];
        float4 v = *(const float4*)&emb[(long)xr * 32 + fg];
        e4[i] = v;
        s.x += v.x; s.y += v.y; s.z += v.z; s.w += v.w;
        q.x += v.x * v.x; q.y += v.y * v.y; q.z += v.z * v.z; q.w += v.w * v.w;
    }
    stats_block_reduce(s, q, sum, sumsq);
}

// GraphNorm -> per-feature affine A,B.  y = A*x + B
__global__ void k_affine32(const float* __restrict__ sum, const float* __restrict__ sumsq,
                           const float* __restrict__ w, const float* __restrict__ b,
                           const float* __restrict__ ms, float invN,
                           float* __restrict__ A, float* __restrict__ B) {
    int f = threadIdx.x;  // 32 threads
    float mean = sum[f] * invN;
    float c = ms[f] * mean;
    float var = sumsq[f] * invN - 2.f * c * mean + c * c;
    float rs = rsqrtf(var + EPSF);
    A[f] = w[f] * rs;
    B[f] = b[f] - w[f] * rs * c;
}

// gn0 affine + fold shift through c1_W:  A[f], brow[o] = sum_f B[f]*W[f][o]
__global__ void k_affine_fold(const float* __restrict__ sum, const float* __restrict__ sumsq,
                              const float* __restrict__ w, const float* __restrict__ b,
                              const float* __restrict__ ms, float invN,
                              const float* __restrict__ W,
                              float* __restrict__ A, float* __restrict__ brow) {
    __shared__ float Bl[32];
    int f = threadIdx.x;  // 32 threads
    float mean = sum[f] * invN;
    float c = ms[f] * mean;
    float var = sumsq[f] * invN - 2.f * c * mean + c * c;
    float rs = rsqrtf(var + EPSF);
    A[f] = w[f] * rs;
    Bl[f] = b[f] - w[f] * rs * c;
    __syncthreads();
    float s = 0.f;
    #pragma unroll
    for (int f2 = 0; f2 < 32; f2++) s += Bl[f2] * W[f2 * 32 + f];
    brow[f] = s;
}

// u[i][o] = (sum_f (A[f]*e[i][f]) * W[f][o] + brow[o]) * dscale[i]
__global__ void k_mm32s(const float* __restrict__ e, const float* __restrict__ W,
                        const float* __restrict__ A, const float* __restrict__ brow,
                        const float* __restrict__ dscale, float* __restrict__ t, int n) {
    __shared__ float Wp[32][32];
    __shared__ float rows[8][32];
    int lt = threadIdx.x;
    for (int k = lt; k < 1024; k += 256) {
        int f = k >> 5;
        Wp[f][k & 31] = A[f] * W[k];
    }
    int nl = lt >> 5, o = lt & 31;
    int node = blockIdx.x * 8 + nl;
    if (node < n) rows[nl][o] = e[(long)node * 32 + o];
    __syncthreads();
    if (node < n) {
        float acc = brow[o];
        #pragma unroll
        for (int f = 0; f < 32; f++) acc += rows[nl][f] * Wp[f][o];
        t[(long)node * 32 + o] = acc * dscale[node];
    }
}

// hw[i][o] = sum_f relu(A[f]*g[i][f]+B[f]) * W[f][o]   (fused gn1 affine+ReLU)
__global__ void k_mm32_relu_in(const float* __restrict__ g, const float* __restrict__ W,
                               const float* __restrict__ A, const float* __restrict__ B,
                               float* __restrict__ hw, int n) {
    __shared__ float Wp[32][32];
    __shared__ float rows[8][32];
    int lt = threadIdx.x;
    for (int k = lt; k < 1024; k += 256) {
        Wp[k >> 5][k & 31] = W[k];
    }
    int nl = lt >> 5, o = lt & 31;
    int node = blockIdx.x * 8 + nl;
    if (node < n) rows[nl][o] = fmaxf(A[o] * g[(long)node * 32 + o] + B[o], 0.f);
    __syncthreads();
    if (node < n) {
        float acc = 0.f;
        #pragma unroll
        for (int f = 0; f < 32; f++) acc += rows[nl][f] * Wp[f][o];
        hw[(long)node * 32 + o] = acc;
    }
}

// ---------------- degree via LDS partial histograms (no global atomics) ----------------
// groups: NR1 groups for graph1 cols, NR2 for graph2. BPG blocks per group; each
// block scans a 1/BPG slice of its graph's col list, filters to its 16K range,
// LDS-atomic counts, flushes full histogram non-atomically to its private slab.
__global__ __launch_bounds__(256) void k_deg_hist(const int* __restrict__ e1col,
                                                  const int* __restrict__ e2col,
                                                  int* __restrict__ pbuf) {
    __shared__ int h[RANGE];   // 64 KB
    int tid = threadIdx.x;
    for (int i = tid; i < RANGE; i += 256) h[i] = 0;
    __syncthreads();
    int gid = blockIdx.x / BPG;
    int blk = blockIdx.x % BPG;
    const int* col; long ne; int base;
    if (gid < NR1) { col = e1col; ne = E1N; base = gid * RANGE; }
    else           { col = e2col; ne = E2N; base = (gid - NR1) * RANGE; }
    for (long i = (long)blk * 256 + tid; i < ne; i += (long)BPG * 256) {
        unsigned c = (unsigned)(col[i] - base);
        if (c < RANGE) atomicAdd(&h[c], 1);
    }
    __syncthreads();
    int* dst = pbuf + ((size_t)gid * BPG + blk) * RANGE;
    for (int i = tid; i < RANGE; i += 256) dst[i] = h[i];
}

// reduce BPG partials per node -> dinv = rsqrt(deg+1); handles both graphs
__global__ void k_deg_reduce(const int* __restrict__ pbuf,
                             float* __restrict__ d1, float* __restrict__ d2) {
    int idx = blockIdx.x * 256 + threadIdx.x;
    if (idx < N_NODES) {
        int g = idx / RANGE, off = idx % RANGE;
        const int* p = pbuf + ((size_t)g * BPG) * RANGE + off;
        int s = 0;
        #pragma unroll
        for (int b = 0; b < BPG; b++) s += p[(size_t)b * RANGE];
        d1[idx] = rsqrtf((float)s + 1.f);
    } else if (idx - N_NODES < M_PAIRS) {
        int j = idx - N_NODES;
        int g = j / RANGE, off = j % RANGE;
        const int* p = pbuf + ((size_t)(NR1 + g) * BPG) * RANGE + off;
        int s = 0;
        #pragma unroll
        for (int b = 0; b < BPG; b++) s += p[(size_t)b * RANGE];
        d2[j] = rsqrtf((float)s + 1.f);
    }
}

// coalesced atomic scatter: agg[col][f] += u[row][f]
// one thread per (edge, feature): 32 consecutive lanes -> one dest row
__global__ void k_scatter(const int* __restrict__ row, const int* __restrict__ col,
                          const float* __restrict__ u, float* __restrict__ agg, int ne) {
    long idx = (long)blockIdx.x * 256 + threadIdx.x;
    if (idx >= (long)ne * 32) return;
    int e = (int)(idx >> 5), f = (int)idx & 31;
    atomicAdd(&agg[(long)col[e] * 32 + f], u[(long)row[e] * 32 + f]);
}

// epilogue: agg = dinv[i]*(agg + u) + bias, fused GraphNorm stats accumulation
__global__ void k_selfbias_stats(float* __restrict__ agg, const float* __restrict__ u,
                                 const float* __restrict__ dinv, const float* __restrict__ bias,
                                 float* __restrict__ sum, float* __restrict__ sumsq, int n) {
    long n4 = (long)n * 8;
    float4 s = {0,0,0,0}, q = {0,0,0,0};
    float4* a4 = (float4*)agg;
    const float4* u4 = (const float4*)u;
    long stride = (long)gridDim.x * 256;
    for (long idx = (long)blockIdx.x * 256 + threadIdx.x; idx < n4; idx += stride) {
        int i = (int)(idx >> 3), fg = ((int)idx & 7) * 4;
        float dc = dinv[i];
        float4 a = a4[idx];
        float4 uv = u4[idx];
        float4 b = *(const float4*)&bias[fg];
        float4 r;
        r.x = dc * (a.x + uv.x) + b.x;
        r.y = dc * (a.y + uv.y) + b.y;
        r.z = dc * (a.z + uv.z) + b.z;
        r.w = dc * (a.w + uv.w) + b.w;
        a4[idx] = r;
        s.x += r.x; s.y += r.y; s.z += r.z; s.w += r.w;
        q.x += r.x * r.x; q.y += r.y * r.y; q.z += r.z * r.z; q.w += r.w * r.w;
    }
    stats_block_reduce(s, q, sum, sumsq);
}

__global__ void k_mask(const int* __restrict__ pos2, int* __restrict__ mask, int p) {
    int i = blockIdx.x * 256 + threadIdx.x;
    if (i < p) mask[pos2[i]] = 1;
}

__global__ void k_maskcnt(const int* __restrict__ mask, int* __restrict__ cnt, int m) {
    __shared__ int sd[256];
    int idx = blockIdx.x * 256 + threadIdx.x;
    sd[threadIdx.x] = (idx < m) ? mask[idx] : 0;
    __syncthreads();
    for (int s = 128; s > 0; s >>= 1) {
        if (threadIdx.x < s) sd[threadIdx.x] += sd[threadIdx.x + s];
        __syncthreads();
    }
    if (threadIdx.x == 0) atomicAdd(cnt, sd[0]);
}

// z has only two distinct rows (mask 0/1); zc{0,1}[o] = z{0,1} @ c2_W[32:48]
__global__ void k_zcalc(const float* __restrict__ emb2, const float* __restrict__ w,
                        const float* __restrict__ b, const float* __restrict__ ms,
                        const int* __restrict__ cnt, const float* __restrict__ c2W,
                        float* __restrict__ zc0, float* __restrict__ zc1) {
    __shared__ float z0[16], z1[16];
    int t = threadIdx.x;  // 32 threads
    const float Mf = (float)M_PAIRS;
    if (t < 16) {
        float e0 = emb2[t], e1 = emb2[16 + t];
        float c1f = (float)(*cnt);
        float mean = (c1f * e1 + (Mf - c1f) * e0) / Mf;
        float c = ms[t] * mean;
        float d0 = e0 - c, d1 = e1 - c;
        float var = (c1f * d1 * d1 + (Mf - c1f) * d0 * d0) / Mf;
        float rs = rsqrtf(var + EPSF);
        z0[t] = w[t] * d0 * rs + b[t];
        z1[t] = w[t] * d1 * rs + b[t];
    }
    __syncthreads();
    float s0 = 0.f, s1 = 0.f;
    #pragma unroll
    for (int f = 0; f < 16; f++) {
        float wv = c2W[(32 + f) * 32 + t];
        s0 += z0[f] * wv;
        s1 += z1[f] * wv;
    }
    zc0[t] = s0;
    zc1[t] = s1;
}

// t2[j][fg..] = (hw[a][fg..] + hw[b][fg..] + zc_{mask[j]}[fg..]) * d2[j]
__global__ void k_t2(const float* __restrict__ hw, const int* __restrict__ pos1,
                     const int* __restrict__ mask, const float* __restrict__ zc0,
                     const float* __restrict__ zc1, const float* __restrict__ d2,
                     float* __restrict__ t2, int m) {
    long idx = (long)blockIdx.x * 256 + threadIdx.x;
    if (idx >= (long)m * 8) return;
    int j = (int)(idx >> 3), fg = ((int)idx & 7) * 4;
    int a = pos1[2 * j], b = pos1[2 * j + 1];
    const float* zc = mask[j] ? zc1 : zc0;
    float dj = d2[j];
    float4 va = *(const float4*)&hw[(long)a * 32 + fg];
    float4 vb = *(const float4*)&hw[(long)b * 32 + fg];
    float4 vz = *(const float4*)&zc[fg];
    float4 r;
    r.x = (va.x + vb.x + vz.x) * dj;
    r.y = (va.y + vb.y + vz.y) * dj;
    r.z = (va.z + vb.z + vz.z) * dj;
    r.w = (va.w + vb.w + vz.w) * dj;
    *(float4*)&t2[idx * 4] = r;
}

// out[k] = relu(A*g2[pos2[k]]+B) . predW + predb
__global__ void k_pred(const float* __restrict__ g2, const int* __restrict__ pos2,
                       const float* __restrict__ A, const float* __restrict__ B,
                       const float* __restrict__ predW, const float* __restrict__ predb,
                       float* __restrict__ out, int p) {
    int k = blockIdx.x * 256 + threadIdx.x;
    if (k >= p) return;
    int j = pos2[k];
    float s = predb[0];
    #pragma unroll
    for (int o = 0; o < 32; o++)
        s += fmaxf(A[o] * g2[(long)j * 32 + o] + B[o], 0.f) * predW[o];
    out[k] = s;
}

extern "C" void kernel_launch(void* const* d_in, const int* in_sizes, int n_in,
                              void* d_out, int out_size, void* d_ws, size_t ws_size,
                              hipStream_t stream) {
    const int*   x      = (const int*)d_in[0];
    const int*   e1row  = (const int*)d_in[1];
    const int*   e1col  = e1row + E1N;
    const int*   e2row  = (const int*)d_in[2];
    const int*   e2col  = e2row + E2N;
    const int*   pos1   = (const int*)d_in[3];
    const int*   pos2   = (const int*)d_in[4];
    const float* emb1   = (const float*)d_in[5];
    const float* gn0_w  = (const float*)d_in[6];
    const float* gn0_b  = (const float*)d_in[7];
    const float* gn0_ms = (const float*)d_in[8];
    const float* c1_W   = (const float*)d_in[9];
    const float* c1_b   = (const float*)d_in[10];
    const float* gn1_w  = (const float*)d_in[11];
    const float* gn1_b  = (const float*)d_in[12];
    const float* gn1_ms = (const float*)d_in[13];
    const float* emb2   = (const float*)d_in[14];
    const float* gn2_w  = (const float*)d_in[15];
    const float* gn2_b  = (const float*)d_in[16];
    const float* gn2_ms = (const float*)d_in[17];
    const float* c2_W   = (const float*)d_in[18];
    const float* c2_b   = (const float*)d_in[19];
    const float* gn3_w  = (const float*)d_in[20];
    const float* gn3_b  = (const float*)d_in[21];
    const float* gn3_ms = (const float*)d_in[22];
    const float* predW  = (const float*)d_in[23];
    const float* predb  = (const float*)d_in[24];
    float* out = (float*)d_out;

    // ---------------- workspace arena (floats) ----------------
    const size_t N32 = (size_t)N_NODES * 32;
    const size_t M32 = (size_t)M_PAIRS * 32;
    float* fw = (float*)d_ws;
    size_t off = 0;
    auto alloc = [&](size_t n) { float* p = fw + off; off += n; return p; };
    float* e    = alloc(N32);               // alias hw later
    float* t    = alloc(N32);               // u1 = (gn0(e)@W + brow) * d1
    float* t2   = alloc(M32);               // u2
    int*   pbuf = (int*)alloc((size_t)(NR1 + NR2) * BPG * RANGE);  // ~35.7 MB
    float* d1   = alloc(N_NODES);
    float* d2   = alloc(M_PAIRS);
    // ---- contiguous zero region ----
    float* agg  = alloc(N32);
    float* agg2 = alloc(M32);
    int*   mask = (int*)alloc(M_PAIRS);
    float* st   = alloc(S_TOTAL);
    float* hw   = e;  // alias: e dead after k_mm32s

    const size_t zero_bytes = (N32 + M32 + (size_t)M_PAIRS + S_TOTAL) * 4;
    hipMemsetAsync(agg, 0, zero_bytes, stream);

    auto cdiv = [](long a, long b) { return (int)((a + b - 1) / b); };
    const float invN = 1.f / (float)N_NODES;
    const float invM = 1.f / (float)M_PAIRS;

    // ---- degrees via LDS partial histograms (no global atomics) ----
    k_deg_hist<<<(NR1 + NR2) * BPG, 256, 0, stream>>>(e1col, e2col, pbuf);
    k_deg_reduce<<<cdiv((long)N_NODES + M_PAIRS, 256), 256, 0, stream>>>(pbuf, d1, d2);

    // ---- stage 0: embedding + gn0 stats ----
    k_embed_stats<<<RED_BLOCKS, 256, 0, stream>>>(emb1, x, e, st + S0_SUM, st + S0_SQ, N_NODES);
    k_affine_fold<<<1, 32, 0, stream>>>(st + S0_SUM, st + S0_SQ, gn0_w, gn0_b, gn0_ms, invN,
                                        c1_W, st + S_A0, st + S_B0ROW);

    // ---- conv1: u1 = (gn0(e) @ c1_W) * d1 ; scatter ; epilogue+gn1 stats ----
    k_mm32s<<<cdiv(N_NODES, 8), 256, 0, stream>>>(e, c1_W, st + S_A0, st + S_B0ROW, d1, t, N_NODES);
    k_scatter<<<cdiv((long)E1N * 32, 256), 256, 0, stream>>>(e1row, e1col, t, agg, E1N);
    k_selfbias_stats<<<RED_BLOCKS, 256, 0, stream>>>(agg, t, d1, c1_b,
                                                     st + S1_SUM, st + S1_SQ, N_NODES);
    k_affine32<<<1, 32, 0, stream>>>(st + S1_SUM, st + S1_SQ, gn1_w, gn1_b, gn1_ms, invN,
                                     st + S_A1, st + S_B1);
    k_mm32_relu_in<<<cdiv(N_NODES, 8), 256, 0, stream>>>(agg, c2_W, st + S_A1, st + S_B1,
                                                         hw, N_NODES);

    // ---- mask / z path ----
    k_mask<<<cdiv(P_OUT, 256), 256, 0, stream>>>(pos2, mask, P_OUT);
    k_maskcnt<<<cdiv(M_PAIRS, 256), 256, 0, stream>>>(mask, (int*)(st + S_CNT), M_PAIRS);
    k_zcalc<<<1, 32, 0, stream>>>(emb2, gn2_w, gn2_b, gn2_ms, (const int*)(st + S_CNT),
                                  c2_W, st + S_ZC0, st + S_ZC1);

    // ---- conv2: u2 = (hw[a]+hw[b]+zc) * d2 ; scatter ; epilogue+gn3 stats ----
    k_t2<<<cdiv((long)M_PAIRS * 8, 256), 256, 0, stream>>>(hw, pos1, mask, st + S_ZC0,
                                                           st + S_ZC1, d2, t2, M_PAIRS);
    k_scatter<<<cdiv((long)E2N * 32, 256), 256, 0, stream>>>(e2row, e2col, t2, agg2, E2N);
    k_selfbias_stats<<<RED_BLOCKS, 256, 0, stream>>>(agg2, t2, d2, c2_b,
                                                     st + S3_SUM, st + S3_SQ, M_PAIRS);
    k_affine32<<<1, 32, 0, stream>>>(st + S3_SUM, st + S3_SQ, gn3_w, gn3_b, gn3_ms, invM,
                                     st + S_A3, st + S_B3);
    k_pred<<<cdiv(P_OUT, 256), 256, 0, stream>>>(agg2, pos2, st + S_A3, st + S_B3,
                                                 predW, predb, out, P_OUT);
}